// Round 2
// baseline (4156.427 us; speedup 1.0000x reference)
//
#include <hip/hip_runtime.h>

#define T_STEPS 128
#define BATCH   2048
#define IN_F    64
#define HID     256
#define OUT_F   16
#define ROWS    2     // batch rows per block
#define CH      16    // timesteps of x staged per LDS chunk

typedef __attribute__((address_space(3))) void lds_void;
typedef const __attribute__((address_space(1))) void gbl_void;

// Zero the spikes_mean accumulator (d_out is not re-poisoned between replays).
__global__ void snn_init_kernel(float* __restrict__ out) {
    if (threadIdx.x == 0 && blockIdx.x == 0) out[BATCH * OUT_F] = 0.0f;
}

// Block = 2 batch rows; thread = hidden neuron (both rows); 128 steps fused.
__global__ void __launch_bounds__(256)
__attribute__((amdgpu_waves_per_eu(4, 4)))
snn_fused_kernel(const float* __restrict__ x,
                 const float* __restrict__ w1,
                 const float* __restrict__ w2,
                 float* __restrict__ out) {
    const int tid  = threadIdx.x;
    const int lane = tid & 63;
    const int wv   = tid >> 6;
    const int oo   = tid & 15;   // layer-2 output index
    const int cc   = tid >> 4;   // layer-2 hidden chunk (16 wide)
    const int row0 = blockIdx.x * ROWS;

    __shared__ float xlds[2][CH][ROWS][IN_F];   // 16 KB, double-buffered chunks
    __shared__ float zbuf[2][ROWS][HID];        // 4 KB, double-buffered steps
    __shared__ float wsum[2][4][ROWS][OUT_F];   // 1 KB, double-buffered steps
    __shared__ float sacc;
    if (tid == 0) sacc = 0.0f;

    const float dt_tau = (float)(0.001 * (1.0 / 0.006));      // 1/6
    const float decay  = (float)(1.0 - 0.001 * (1.0 / 0.006)); // 5/6

    // Persistent weights in VGPRs (compile-time indices only).
    float wr[IN_F];
#pragma unroll
    for (int k = 0; k < IN_F; k += 4) {
        const float4 v = *reinterpret_cast<const float4*>(&w1[tid * IN_F + k]);
        wr[k] = v.x; wr[k + 1] = v.y; wr[k + 2] = v.z; wr[k + 3] = v.w;
    }
    float w2r[16];
#pragma unroll
    for (int j = 0; j < 16; j += 4) {
        const float4 v = *reinterpret_cast<const float4*>(&w2[oo * HID + cc * 16 + j]);
        w2r[j] = v.x; w2r[j + 1] = v.y; w2r[j + 2] = v.z; w2r[j + 3] = v.w;
    }

    float v1[ROWS] = {0.f, 0.f}, i1[ROWS] = {0.f, 0.f};
    float scnt = 0.f;
    float v2 = 0.f, i2 = 0.f, ymax = -1e30f;   // live only in tid<32

    // Async stage of one CH-step x chunk into xlds[nb].
    // LDS dest is wave-uniform base + lane*16 (linear): 1 KB = 2 steps of
    // (2 rows x 64 floats); lane>>5 selects which of the 2 steps in the
    // matching per-lane GLOBAL source address. Wave wv covers steps [4wv,4wv+4).
    auto stage_chunk = [&](int t0n, int nb) {
#pragma unroll
        for (int i = 0; i < 2; ++i) {
            const int sl = 4 * wv + 2 * i;                 // wave-uniform step base
            const int tn = t0n + sl + (lane >> 5);         // per-lane step
            const float* src =
                x + ((size_t)tn * BATCH + row0) * IN_F + (lane & 31) * 4;
            __builtin_amdgcn_global_load_lds((gbl_void*)src,
                                             (lds_void*)&xlds[nb][sl][0][0],
                                             16, 0, 0);
        }
    };

    stage_chunk(0, 0);
    __syncthreads();   // drains vmcnt -> chunk 0 resident & visible

    int cb = 0;
    for (int t = 0; t < T_STEPS; ++t) {
        const int s = t & (CH - 1);
        const int b = t & 1;

        // ---- layer 1: g1 = dot(x_t, w1[tid]) per row, x via LDS broadcast ----
        float g1r[ROWS];
#pragma unroll
        for (int r = 0; r < ROWS; ++r) {
            float a0 = 0.f, a1 = 0.f, a2 = 0.f, a3 = 0.f;
#pragma unroll
            for (int k = 0; k < IN_F; k += 4) {
                const float4 xv =
                    *reinterpret_cast<const float4*>(&xlds[cb][s][r][k]);
                a0 = fmaf(xv.x, wr[k + 0], a0);
                a1 = fmaf(xv.y, wr[k + 1], a1);
                a2 = fmaf(xv.z, wr[k + 2], a2);
                a3 = fmaf(xv.w, wr[k + 3], a3);
            }
            g1r[r] = (a0 + a1) + (a2 + a3);
        }

        // ---- LIF update (expression forms identical to reference) ----
#pragma unroll
        for (int r = 0; r < ROWS; ++r) {
            const float v_dec = fmaf(dt_tau, i1[r] - v1[r], v1[r]);
            const float i_dec = i1[r] * decay;
            const bool  spk   = v_dec > 1.0f;
            v1[r] = spk ? 0.0f : v_dec;
            i1[r] = i_dec + g1r[r];
            const float z = spk ? 1.0f : 0.0f;
            scnt += z;
            zbuf[b][r][tid] = z;
        }

        __syncthreads();   // the ONLY barrier per step

        // ---- prefetch next x chunk (once per chunk, right after a barrier) ----
        if (s == 0 && t + CH < T_STEPS) stage_chunk(t + CH, cb ^ 1);

        // ---- LI update for step t-1 (pipelined; wsum[b^1] visible now) ----
        if (t > 0 && tid < 32) {
            const int rr = tid >> 4;
            const int pb = b ^ 1;
            const float g2 = (wsum[pb][0][rr][oo] + wsum[pb][1][rr][oo]) +
                             (wsum[pb][2][rr][oo] + wsum[pb][3][rr][oo]);
            v2 = fmaf(dt_tau, i2 - v2, v2);
            i2 = i2 * decay + g2;
            ymax = fmaxf(ymax, v2);
        }

        // ---- layer-2 partials for step t (reads zbuf[b], writes wsum[b]) ----
        float p0 = 0.f, p1 = 0.f;
#pragma unroll
        for (int j = 0; j < 16; j += 4) {
            const float4 z0 =
                *reinterpret_cast<const float4*>(&zbuf[b][0][cc * 16 + j]);
            const float4 z1 =
                *reinterpret_cast<const float4*>(&zbuf[b][1][cc * 16 + j]);
            p0 = fmaf(z0.x, w2r[j + 0], p0); p0 = fmaf(z0.y, w2r[j + 1], p0);
            p0 = fmaf(z0.z, w2r[j + 2], p0); p0 = fmaf(z0.w, w2r[j + 3], p0);
            p1 = fmaf(z1.x, w2r[j + 0], p1); p1 = fmaf(z1.y, w2r[j + 1], p1);
            p1 = fmaf(z1.z, w2r[j + 2], p1); p1 = fmaf(z1.w, w2r[j + 3], p1);
        }
        p0 += __shfl_xor(p0, 16, 64); p0 += __shfl_xor(p0, 32, 64);
        p1 += __shfl_xor(p1, 16, 64); p1 += __shfl_xor(p1, 32, 64);
        if (lane < 16) { wsum[b][wv][0][lane] = p0; wsum[b][wv][1][lane] = p1; }

        if (s == CH - 1) cb ^= 1;
    }

    // ---- drain: LI update for t = 127 (wsum[1]) + write scores ----
    __syncthreads();
    if (tid < 32) {
        const int rr = tid >> 4;
        const float g2 = (wsum[1][0][rr][oo] + wsum[1][1][rr][oo]) +
                         (wsum[1][2][rr][oo] + wsum[1][3][rr][oo]);
        v2 = fmaf(dt_tau, i2 - v2, v2);
        i2 = i2 * decay + g2;
        ymax = fmaxf(ymax, v2);
        out[(row0 + rr) * OUT_F + oo] = ymax;
    }

    // ---- spikes: wave reduce -> LDS atomic -> one global atomic (exact ints) ----
#pragma unroll
    for (int m = 1; m < 64; m <<= 1) scnt += __shfl_xor(scnt, m, 64);
    if (lane == 0) atomicAdd(&sacc, scnt);
    __syncthreads();
    if (tid == 0) atomicAdd(&out[BATCH * OUT_F], sacc * (1.0f / BATCH));
}

extern "C" void kernel_launch(void* const* d_in, const int* in_sizes, int n_in,
                              void* d_out, int out_size, void* d_ws, size_t ws_size,
                              hipStream_t stream) {
    const float* x  = (const float*)d_in[0];
    const float* w1 = (const float*)d_in[1];
    const float* w2 = (const float*)d_in[2];
    float* out = (float*)d_out;

    hipLaunchKernelGGL(snn_init_kernel, dim3(1), dim3(64), 0, stream, out);
    hipLaunchKernelGGL(snn_fused_kernel, dim3(BATCH / ROWS), dim3(256), 0, stream,
                       x, w1, w2, out);
}

// Round 3
// 90.803 us; speedup vs baseline: 45.7742x; 45.7742x over previous
//
#include <hip/hip_runtime.h>

#define T_STEPS 128
#define BATCH   2048
#define IN_F    64
#define HID     256
#define OUT_F   16
#define BTILE   8                 // real batch rows per block (M=16 MFMA, rows 8-15 padded)
#define CH      8                 // timesteps of x per LDS chunk
#define NBLK    (BATCH / BTILE)   // 256 blocks = 1/CU

typedef __attribute__((ext_vector_type(8))) short bf16x8;   // MFMA A/B frag (4 VGPR)
typedef __attribute__((ext_vector_type(4))) float f32x4;    // MFMA C/D frag
typedef unsigned short u16;
typedef unsigned int   u32;

__device__ __forceinline__ u16 f2bf(float f) {              // RNE f32->bf16
    u32 u = __float_as_uint(f);
    u += 0x7fffu + ((u >> 16) & 1u);
    return (u16)(u >> 16);
}

__device__ __forceinline__ bf16x8 pack8(float4 a, float4 b) {
    bf16x8 r;
    r[0] = (short)f2bf(a.x); r[1] = (short)f2bf(a.y);
    r[2] = (short)f2bf(a.z); r[3] = (short)f2bf(a.w);
    r[4] = (short)f2bf(b.x); r[5] = (short)f2bf(b.y);
    r[6] = (short)f2bf(b.z); r[7] = (short)f2bf(b.w);
    return r;
}

// Zero the spikes_mean accumulator (d_out not re-poisoned between replays).
__global__ void snn_init_kernel(float* __restrict__ out) {
    if (threadIdx.x == 0 && blockIdx.x == 0) out[BATCH * OUT_F] = 0.0f;
}

__global__ void __launch_bounds__(512, 2)
snn_mfma_kernel(const float* __restrict__ x, const float* __restrict__ w1,
                const float* __restrict__ w2, float* __restrict__ out)
{
    const int tid  = threadIdx.x;
    const int lane = tid & 63;
    const int wv   = tid >> 6;          // 8 waves; wave w owns hid [32w, 32w+32)
    const int hi   = lane >> 4;         // 0..3 (frag k-group / C row-group)
    const int l15  = lane & 15;
    const int row0 = blockIdx.x * BTILE;

    // X chunks: [buf][step(8)][row(16)][k(64)] bf16, XOR-swizzled, rows 8-15 stay 0.
    __shared__ __attribute__((aligned(16))) u16 xl[2][CH * 16 * 64];   // 32 KB
    // Spikes: [step parity][row(16)][hid(256)] bf16, swizzled, rows 8-15 stay 0.
    __shared__ __attribute__((aligned(16))) u16 zb[2][16 * 256];       // 16 KB
    __shared__ float sacc;

    // ---- zero xl + zb once (padding rows are never rewritten) ----
    {
        bf16x8 zz = {};
#pragma unroll
        for (int j = 0; j < 4; ++j)
            ((bf16x8*)&xl[0][0])[tid + 512 * j] = zz;    // 2048 vecs = 32 KB
        ((bf16x8*)&zb[0][0])[tid] = zz;
        ((bf16x8*)&zb[1][0])[tid] = zz;
    }
    if (tid == 0) sacc = 0.f;

    const f32x4 zf = {0.f, 0.f, 0.f, 0.f};
    const float dt_tau = (float)(0.001 * (1.0 / 0.006));       // 1/6
    const float decay  = (float)(1.0 - 0.001 * (1.0 / 0.006)); // 5/6

    // ---- persistent W1 B-frags: B[k][col=hid], col = 32w+16nt+l15, k = 32kt+8hi+i ----
    bf16x8 w1f[2][2];
#pragma unroll
    for (int nt = 0; nt < 2; ++nt)
#pragma unroll
        for (int kt = 0; kt < 2; ++kt) {
            const int col = wv * 32 + nt * 16 + l15;
            const int k0  = kt * 32 + hi * 8;
            const float4 a = *(const float4*)&w1[col * IN_F + k0];
            const float4 b = *(const float4*)&w1[col * IN_F + k0 + 4];
            w1f[nt][kt] = pack8(a, b);
        }

    // ---- persistent W2 B-frags (consumed by wave 0 only): col = o = l15, k over HID ----
    bf16x8 w2f[8];
#pragma unroll
    for (int kt = 0; kt < 8; ++kt) {
        const int k0 = kt * 32 + hi * 8;
        const float4 a = *(const float4*)&w2[l15 * HID + k0];
        const float4 b = *(const float4*)&w2[l15 * HID + k0 + 4];
        w2f[kt] = pack8(a, b);
    }

    // ---- X chunk staging map: thread -> (step, row, k-block); swizzled write ----
    const int cstep = tid >> 6;
    const int crow  = (tid >> 3) & 7;
    const int ck0   = (tid & 7) * 8;
    const size_t gstep = (size_t)BATCH * IN_F;
    const float* gsrc = x + ((size_t)cstep * BATCH + (row0 + crow)) * IN_F + ck0;
    const int wofs = (cstep * 16 + crow) * 64 + (ck0 ^ ((crow & 7) << 3));

    // prologue: chunk 0 -> LDS; chunk 1 -> regs (T14: issue early, write 8 steps later)
    float4 ra = *(const float4*)(gsrc);
    float4 rb = *(const float4*)(gsrc + 4);
    *(bf16x8*)&xl[0][wofs] = pack8(ra, rb);
    ra = *(const float4*)(gsrc + CH * gstep);
    rb = *(const float4*)(gsrc + CH * gstep + 4);

    // ---- per-lane recurrent state, lives in C-frag layout ----
    f32x4 v1[2], i1[2];
    v1[0] = zf; v1[1] = zf; i1[0] = zf; i1[1] = zf;
    f32x4 v2 = zf, i2 = zf;
    f32x4 ymax = {-1e30f, -1e30f, -1e30f, -1e30f};
    float scnt = 0.f;

    const int sw = (l15 & 7) << 3;   // read-side XOR swizzle (row = l15)

    __syncthreads();

    for (int t = 0; t < T_STEPS; ++t) {
        const int cb = (t >> 3) & 1;
        const int ph = t & 7;
        const int sb = t & 1;

        // A-frags: X[row=l15][k=32kt+8hi+i] via conflict-free swizzled ds_read_b128
        const u16* xr = &xl[cb][(ph * 16 + l15) * 64];
        const bf16x8 xf0 = *(const bf16x8*)&xr[(hi * 8) ^ sw];
        const bf16x8 xf1 = *(const bf16x8*)&xr[(32 + hi * 8) ^ sw];

        // layer 1: G1[16, 32w+16nt..+16) , K=64 in two MFMAs
        f32x4 g1[2];
#pragma unroll
        for (int nt = 0; nt < 2; ++nt) {
            g1[nt] = __builtin_amdgcn_mfma_f32_16x16x32_bf16(xf0, w1f[nt][0], zf, 0, 0, 0);
            g1[nt] = __builtin_amdgcn_mfma_f32_16x16x32_bf16(xf1, w1f[nt][1], g1[nt], 0, 0, 0);
        }

        // LIF elementwise in C-frag layout: row = 4hi+r (rows 8-15 padding), col = l15
        u16* zrow = &zb[sb][0];
#pragma unroll
        for (int nt = 0; nt < 2; ++nt) {
#pragma unroll
            for (int r = 0; r < 4; ++r) {
                const float vd = fmaf(dt_tau, i1[nt][r] - v1[nt][r], v1[nt][r]);
                const float id = i1[nt][r] * decay;
                const bool  s  = vd > 1.0f;
                v1[nt][r] = s ? 0.f : vd;
                i1[nt][r] = id + g1[nt][r];
                scnt += s ? 1.f : 0.f;
                if (lane < 32) {                      // real rows 0-7 live in lanes 0-31
                    const int zr = hi * 4 + r;
                    const int zc = wv * 32 + nt * 16 + l15;
                    zrow[zr * 256 + (zc ^ ((zr & 7) << 3))] = s ? (u16)0x3F80 : (u16)0;
                }
            }
        }

        // chunk staging: write regs (chunk c+1) to the dead buffer; issue loads for c+2
        if (ph == 0) {
            if (t + CH < T_STEPS)
                *(bf16x8*)&xl[cb ^ 1][wofs] = pack8(ra, rb);
            if (t + 2 * CH < T_STEPS) {
                const float* g = gsrc + (size_t)(t + 2 * CH) * gstep;
                ra = *(const float4*)g;
                rb = *(const float4*)(g + 4);
            }
        }

        __syncthreads();   // publishes z(t); xl reads of step t already done above

        // layer 2 + LI recurrence: wave 0 only, on z(t); others run ahead to t+1
        if (wv == 0) {
            f32x4 g2 = zf;
            const u16* zr2 = &zb[sb][l15 * 256];
#pragma unroll
            for (int kt = 0; kt < 8; ++kt) {
                const bf16x8 zfr = *(const bf16x8*)&zr2[(kt * 32 + hi * 8) ^ sw];
                g2 = __builtin_amdgcn_mfma_f32_16x16x32_bf16(zfr, w2f[kt], g2, 0, 0, 0);
            }
#pragma unroll
            for (int r = 0; r < 4; ++r) {
                v2[r]   = fmaf(dt_tau, i2[r] - v2[r], v2[r]);
                i2[r]   = i2[r] * decay + g2[r];
                ymax[r] = fmaxf(ymax[r], v2[r]);
            }
        }
    }

    // scores: wave 0, lanes 0-31 hold rows 0-7 (row = 4hi+r), col = o = l15
    if (wv == 0 && lane < 32) {
#pragma unroll
        for (int r = 0; r < 4; ++r)
            out[(row0 + hi * 4 + r) * OUT_F + l15] = ymax[r];
    }

    // spikes: wave shuffle reduce -> LDS -> one global atomic (integer-exact)
#pragma unroll
    for (int m = 1; m < 64; m <<= 1) scnt += __shfl_xor(scnt, m, 64);
    if (lane == 0) atomicAdd(&sacc, scnt);
    __syncthreads();
    if (tid == 0) atomicAdd(&out[BATCH * OUT_F], sacc * (1.0f / BATCH));
}

extern "C" void kernel_launch(void* const* d_in, const int* in_sizes, int n_in,
                              void* d_out, int out_size, void* d_ws, size_t ws_size,
                              hipStream_t stream) {
    const float* x  = (const float*)d_in[0];
    const float* w1 = (const float*)d_in[1];
    const float* w2 = (const float*)d_in[2];
    float* out = (float*)d_out;

    hipLaunchKernelGGL(snn_init_kernel, dim3(1), dim3(64), 0, stream, out);
    hipLaunchKernelGGL(snn_mfma_kernel, dim3(NBLK), dim3(512), 0, stream,
                       x, w1, w2, out);
}

// Round 4
// 77.332 us; speedup vs baseline: 53.7480x; 1.1742x over previous
//
#include <hip/hip_runtime.h>

#define T_STEPS 128
#define BATCH   2048
#define IN_F    64
#define HID     256
#define OUT_F   16
#define CH      8                  // timesteps per staged x chunk
#define TROWS   16                 // real batch rows per block (full M=16)
#define HHALF   128                // hid columns per block
#define NCHUNK  (T_STEPS / CH)     // 16
#define SLAB    (BATCH * OUT_F)    // 32768 floats per timestep of g2

typedef __attribute__((ext_vector_type(8))) short bf16x8;
typedef __attribute__((ext_vector_type(4))) float f32x4;
typedef unsigned short u16;
typedef unsigned int   u32;

__device__ __forceinline__ u16 f2bf(float f) {              // RNE f32->bf16
    u32 u = __float_as_uint(f);
    u += 0x7fffu + ((u >> 16) & 1u);
    return (u16)(u >> 16);
}
__device__ __forceinline__ float bf2f(u16 h) {
    return __uint_as_float(((u32)h) << 16);
}
__device__ __forceinline__ bf16x8 pack8(float4 a, float4 b) {
    bf16x8 r;
    r[0] = (short)f2bf(a.x); r[1] = (short)f2bf(a.y);
    r[2] = (short)f2bf(a.z); r[3] = (short)f2bf(a.w);
    r[4] = (short)f2bf(b.x); r[5] = (short)f2bf(b.y);
    r[6] = (short)f2bf(b.z); r[7] = (short)f2bf(b.w);
    return r;
}

// Zero the spikes_mean accumulator (d_out not re-poisoned between replays).
__global__ void snn_init_kernel(float* __restrict__ out) {
    if (threadIdx.x == 0 && blockIdx.x == 0) out[BATCH * OUT_F] = 0.0f;
}

// Kernel 1: LIF layer over (16 rows x 128 hid) per block; writes per-step
// partial g2 = z @ w2.T (bf16) to ws. grid 256 = 128 tiles x 2 hid-halves.
__global__ void __launch_bounds__(512, 2)
snn_l1_kernel(const float* __restrict__ x, const float* __restrict__ w1,
              const float* __restrict__ w2, u16* __restrict__ g2p,
              float* __restrict__ out)
{
    const int tid  = threadIdx.x;
    const int lane = tid & 63;
    const int wv   = tid >> 6;
    const int hi   = lane >> 4;
    const int l15  = lane & 15;
    const int tile = blockIdx.x & 127;       // pair halves on the same XCD
    const int half = blockIdx.x >> 7;
    const int row0 = tile * TROWS;

    __shared__ __attribute__((aligned(16))) u16 xl[2][CH * TROWS * IN_F]; // 32 KB
    __shared__ __attribute__((aligned(16))) u16 zb[2][TROWS * HHALF];     // 8 KB
    __shared__ __attribute__((aligned(16))) float wsum[2][4][256];        // 8 KB
    __shared__ float sacc;
    if (tid == 0) sacc = 0.f;

    const f32x4 zf = {0.f, 0.f, 0.f, 0.f};
    const float dt_tau = (float)(0.001 * (1.0 / 0.006));       // 1/6
    const float decay  = (float)(1.0 - 0.001 * (1.0 / 0.006)); // 5/6

    // W1 B-frags: col = hid = half*128 + 16*wv + l15, k = 32kt + 8hi + i
    const int hcol = half * HHALF + wv * 16 + l15;
    bf16x8 w1f[2];
#pragma unroll
    for (int kt = 0; kt < 2; ++kt) {
        const float4 a = *(const float4*)&w1[hcol * IN_F + kt * 32 + hi * 8];
        const float4 b = *(const float4*)&w1[hcol * IN_F + kt * 32 + hi * 8 + 4];
        w1f[kt] = pack8(a, b);
    }
    // W2 B-frag (used by waves 0-3): col = out = l15, k = local hid 32*wv + 8hi + i
    const int k2b = half * HHALF + (wv & 3) * 32 + hi * 8;
    const bf16x8 w2f = pack8(*(const float4*)&w2[l15 * HID + k2b],
                             *(const float4*)&w2[l15 * HID + k2b + 4]);

    // ---- x staging map: 1024 bf16x8 vecs per chunk, 2 per thread ----
    int wofs[2];
    const float* gp[2];
    const size_t cstride = (size_t)CH * BATCH * IN_F;   // floats per chunk
#pragma unroll
    for (int j = 0; j < 2; ++j) {
        const int v  = tid + 512 * j;
        const int vs = v >> 7;            // step in chunk
        const int vr = (v >> 3) & 15;     // row
        const int vk = (v & 7) * 8;       // k base
        wofs[j] = (vs * TROWS + vr) * IN_F + (vk ^ ((vr & 7) << 3));
        gp[j]   = x + ((size_t)vs * BATCH + row0 + vr) * IN_F + vk;
    }
    // prologue: chunk 0 -> LDS, chunk 1 -> regs (T14 split)
    float4 ra[2], rb[2];
#pragma unroll
    for (int j = 0; j < 2; ++j) {
        ra[j] = *(const float4*)gp[j];
        rb[j] = *(const float4*)(gp[j] + 4);
        *(bf16x8*)&xl[0][wofs[j]] = pack8(ra[j], rb[j]);
    }
#pragma unroll
    for (int j = 0; j < 2; ++j) {
        ra[j] = *(const float4*)(gp[j] + cstride);
        rb[j] = *(const float4*)(gp[j] + cstride + 4);
    }

    f32x4 v1 = zf, i1 = zf;
    float scnt = 0.f;
    const int xswz = (l15 & 7) << 3;
    int zoff[4];
#pragma unroll
    for (int r = 0; r < 4; ++r) {
        const int zr = 4 * hi + r;
        zoff[r] = zr * HHALF + ((wv * 16 + l15) ^ ((zr & 15) << 3));
    }
    __syncthreads();

    for (int c = 0; c < NCHUNK; ++c) {
        const u16* xbase = &xl[c & 1][0];
        u16* xdst = &xl[(c + 1) & 1][0];
#pragma unroll
        for (int ph = 0; ph < CH; ++ph) {
            // ---- phase 1: layer 1 + LIF for step t = 8c+ph ----
            const u16* xrow = xbase + (ph * TROWS + l15) * IN_F;
            const bf16x8 xf0 = *(const bf16x8*)(xrow + ((hi * 8) ^ xswz));
            const bf16x8 xf1 = *(const bf16x8*)(xrow + ((32 + hi * 8) ^ xswz));
            f32x4 g1 = __builtin_amdgcn_mfma_f32_16x16x32_bf16(xf0, w1f[0], zf, 0, 0, 0);
            g1 = __builtin_amdgcn_mfma_f32_16x16x32_bf16(xf1, w1f[1], g1, 0, 0, 0);

            u16* zw = &zb[ph & 1][0];
#pragma unroll
            for (int r = 0; r < 4; ++r) {
                const float vd = fmaf(dt_tau, i1[r] - v1[r], v1[r]);
                const float id = i1[r] * decay;
                const bool  s  = vd > 1.0f;
                v1[r] = s ? 0.f : vd;
                i1[r] = id + g1[r];
                scnt += s ? 1.f : 0.f;
                zw[zoff[r]] = s ? (u16)0x3F80 : (u16)0;
            }

            if (ph == 0) {   // chunk staging: write c+1 to dead buffer, load c+2
                if (c < NCHUNK - 1) {
#pragma unroll
                    for (int j = 0; j < 2; ++j)
                        *(bf16x8*)(xdst + wofs[j]) = pack8(ra[j], rb[j]);
                }
                if (c < NCHUNK - 2) {
#pragma unroll
                    for (int j = 0; j < 2; ++j) {
                        const float* g = gp[j] + 2 * cstride;
                        ra[j] = *(const float4*)g;
                        rb[j] = *(const float4*)(g + 4);
                        gp[j] += cstride;
                    }
                }
            }

            __syncthreads();   // the ONLY barrier per step

            // ---- phase 2: distributed layer-2 partials on z(t) ----
            if (wv < 4) {
                const u16* zr2 = &zb[ph & 1][l15 * HHALF];
                const bf16x8 zfr =
                    *(const bf16x8*)(zr2 + ((wv * 32 + hi * 8) ^ (l15 << 3)));
                const f32x4 p =
                    __builtin_amdgcn_mfma_f32_16x16x32_bf16(zfr, w2f, zf, 0, 0, 0);
                *(f32x4*)&wsum[ph & 1][wv][lane * 4] = p;
            } else if (wv == 4 + ((ph + 3) & 3)) {
                // rotating reducer: sum step t-1 partials, store bf16 slab
                if (ph > 0 || c > 0) {
                    const float* wp = &wsum[(ph & 1) ^ 1][0][lane * 4];
                    const f32x4 s0 = *(const f32x4*)(wp);
                    const f32x4 s1 = *(const f32x4*)(wp + 256);
                    const f32x4 s2 = *(const f32x4*)(wp + 512);
                    const f32x4 s3 = *(const f32x4*)(wp + 768);
                    const f32x4 g2 = (s0 + s1) + (s2 + s3);
                    const int tm1 = c * CH + ph - 1;
                    u16* dst = g2p + (size_t)half * (T_STEPS * SLAB)
                             + (size_t)tm1 * SLAB + (row0 + 4 * hi) * OUT_F + l15;
#pragma unroll
                    for (int r = 0; r < 4; ++r) dst[r * OUT_F] = f2bf(g2[r]);
                }
            }
        }
    }

    // drain: slab 127 (parity 1; reducer = wave 7 per rotation)
    __syncthreads();
    if (wv == 7) {
        const float* wp = &wsum[1][0][lane * 4];
        const f32x4 s0 = *(const f32x4*)(wp);
        const f32x4 s1 = *(const f32x4*)(wp + 256);
        const f32x4 s2 = *(const f32x4*)(wp + 512);
        const f32x4 s3 = *(const f32x4*)(wp + 768);
        const f32x4 g2 = (s0 + s1) + (s2 + s3);
        u16* dst = g2p + (size_t)half * (T_STEPS * SLAB)
                 + (size_t)127 * SLAB + (row0 + 4 * hi) * OUT_F + l15;
#pragma unroll
        for (int r = 0; r < 4; ++r) dst[r * OUT_F] = f2bf(g2[r]);
    }

    // spikes: wave reduce -> LDS -> one global atomic (integer-exact)
#pragma unroll
    for (int m = 1; m < 64; m <<= 1) scnt += __shfl_xor(scnt, m, 64);
    if (lane == 0) atomicAdd(&sacc, scnt);
    __syncthreads();
    if (tid == 0) atomicAdd(&out[BATCH * OUT_F], sacc * (1.0f / BATCH));
}

// Kernel 2: LI recurrence + max over t. One thread per (row, out) chain;
// loads are coalesced across threads per timestep slab.
__global__ void __launch_bounds__(128)
snn_li_kernel(const u16* __restrict__ g2p, float* __restrict__ out)
{
    const int gid = blockIdx.x * 128 + threadIdx.x;    // 0..32767
    const u16* p0 = g2p + gid;
    const u16* p1 = g2p + (size_t)T_STEPS * SLAB + gid;
    const float dt_tau = (float)(0.001 * (1.0 / 0.006));
    const float decay  = (float)(1.0 - 0.001 * (1.0 / 0.006));
    float v2 = 0.f, i2 = 0.f, ymax = -1e30f;
#pragma unroll 8
    for (int t = 0; t < T_STEPS; ++t) {
        const float g = bf2f(p0[(size_t)t * SLAB]) + bf2f(p1[(size_t)t * SLAB]);
        v2 = fmaf(dt_tau, i2 - v2, v2);   // uses old i2, matches reference
        ymax = fmaxf(ymax, v2);
        i2 = i2 * decay + g;
    }
    out[gid] = ymax;
}

extern "C" void kernel_launch(void* const* d_in, const int* in_sizes, int n_in,
                              void* d_out, int out_size, void* d_ws, size_t ws_size,
                              hipStream_t stream) {
    const float* x  = (const float*)d_in[0];
    const float* w1 = (const float*)d_in[1];
    const float* w2 = (const float*)d_in[2];
    float* out = (float*)d_out;
    u16* g2p = (u16*)d_ws;   // 2 x 128 x 2048 x 16 bf16 = 16 MB

    hipLaunchKernelGGL(snn_init_kernel, dim3(1), dim3(64), 0, stream, out);
    hipLaunchKernelGGL(snn_l1_kernel, dim3(256), dim3(512), 0, stream,
                       x, w1, w2, g2p, out);
    hipLaunchKernelGGL(snn_li_kernel, dim3(BATCH * OUT_F / 128), dim3(128), 0,
                       stream, g2p, out);
}

// Round 5
// 55.387 us; speedup vs baseline: 75.0435x; 1.3962x over previous
//
#include <hip/hip_runtime.h>

#define T_STEPS 128
#define BATCH   2048
#define IN_F    64
#define HID     256
#define OUT_F   16
#define CH      8                  // timesteps per group / staged x chunk
#define TROWS   16                 // batch rows per block (full M=16, no padding)
#define HHALF   128                // hid columns per block
#define NCHUNK  (T_STEPS / CH)     // 16 groups
#define SLAB    (BATCH * OUT_F)    // elems per timestep of g2 partials

typedef __attribute__((ext_vector_type(8))) short bf16x8;
typedef __attribute__((ext_vector_type(4))) float f32x4;
typedef unsigned short u16;
typedef unsigned int   u32;

__device__ __forceinline__ u16 f2bf(float f) {              // RNE f32->bf16
    u32 u = __float_as_uint(f);
    u += 0x7fffu + ((u >> 16) & 1u);
    return (u16)(u >> 16);
}
__device__ __forceinline__ float bf2f(u16 h) {
    return __uint_as_float(((u32)h) << 16);
}
__device__ __forceinline__ bf16x8 pack8(float4 a, float4 b) {
    bf16x8 r;
    r[0] = (short)f2bf(a.x); r[1] = (short)f2bf(a.y);
    r[2] = (short)f2bf(a.z); r[3] = (short)f2bf(a.w);
    r[4] = (short)f2bf(b.x); r[5] = (short)f2bf(b.y);
    r[6] = (short)f2bf(b.z); r[7] = (short)f2bf(b.w);
    return r;
}

// Zero the spikes_mean accumulator (d_out not re-poisoned between replays).
__global__ void snn_init_kernel(float* __restrict__ out) {
    if (threadIdx.x == 0 && blockIdx.x == 0) out[BATCH * OUT_F] = 0.0f;
}

// Kernel 1: LIF layer, (16 rows x 128 hid) per block, 8 steps per barrier-pair.
// grid 256 = 128 row-tiles x 2 hid-halves (halves paired on the same XCD).
__global__ void __launch_bounds__(512, 2)
snn_l1_kernel(const float* __restrict__ x, const float* __restrict__ w1,
              const float* __restrict__ w2, u16* __restrict__ g2p,
              float* __restrict__ out)
{
    const int tid  = threadIdx.x;
    const int lane = tid & 63;
    const int wv   = tid >> 6;               // 8 waves: wave owns 16 hid cols + 1 step of g2
    const int hi   = lane >> 4;
    const int l15  = lane & 15;
    const int tile = blockIdx.x & 127;
    const int half = blockIdx.x >> 7;
    const int row0 = tile * TROWS;

    __shared__ __attribute__((aligned(16))) u16 xl[CH * TROWS * IN_F];    // 16 KB
    __shared__ __attribute__((aligned(16))) u16 zb[CH * TROWS * HHALF];   // 32 KB
    __shared__ float sacc;
    if (tid == 0) sacc = 0.f;

    const f32x4 zf = {0.f, 0.f, 0.f, 0.f};
    const float dt_tau = (float)(0.001 * (1.0 / 0.006));       // 1/6
    const float decay  = (float)(1.0 - 0.001 * (1.0 / 0.006)); // 5/6

    // W1 B-frags: col = half*128 + 16*wv + l15, k = 32kt + 8hi + i
    const int hcol = half * HHALF + wv * 16 + l15;
    bf16x8 w1f[2];
#pragma unroll
    for (int kt = 0; kt < 2; ++kt)
        w1f[kt] = pack8(*(const float4*)&w1[hcol * IN_F + kt * 32 + hi * 8],
                        *(const float4*)&w1[hcol * IN_F + kt * 32 + hi * 8 + 4]);

    // W2 B-frags (every wave needs full local K=128): col = out = l15
    bf16x8 w2f[4];
#pragma unroll
    for (int kt = 0; kt < 4; ++kt) {
        const int k0 = half * HHALF + kt * 32 + hi * 8;
        w2f[kt] = pack8(*(const float4*)&w2[l15 * HID + k0],
                        *(const float4*)&w2[l15 * HID + k0 + 4]);
    }

    // ---- x staging map: 1024 bf16x8 vecs per chunk, 2 per thread ----
    int wofs[2];
    const float* gp[2];
    const size_t cstride = (size_t)CH * BATCH * IN_F;
#pragma unroll
    for (int j = 0; j < 2; ++j) {
        const int v  = tid + 512 * j;
        const int vs = v >> 7;            // step in chunk
        const int vr = (v >> 3) & 15;     // row
        const int vk = (v & 7) * 8;       // k base (floats)
        wofs[j] = (vs * TROWS + vr) * IN_F + (vk ^ ((vr & 7) << 3));
        gp[j]   = x + ((size_t)vs * BATCH + row0 + vr) * IN_F + vk;
    }
    // prologue: chunk 0 -> LDS; chunk 1 -> regs (written to LDS in phase C of g0)
    float4 ra[2], rb[2];
#pragma unroll
    for (int j = 0; j < 2; ++j) {
        ra[j] = *(const float4*)gp[j];
        rb[j] = *(const float4*)(gp[j] + 4);
        *(bf16x8*)&xl[wofs[j]] = pack8(ra[j], rb[j]);
    }
#pragma unroll
    for (int j = 0; j < 2; ++j) {
        ra[j] = *(const float4*)(gp[j] + cstride);
        rb[j] = *(const float4*)(gp[j] + cstride + 4);
    }

    f32x4 v1 = zf, i1 = zf;
    float scnt = 0.f;
    const int xswz = (l15 & 7) << 3;
    int zoff[4];
#pragma unroll
    for (int r = 0; r < 4; ++r) {
        const int zr = 4 * hi + r;
        zoff[r] = zr * HHALF + ((wv * 16 + l15) ^ ((zr & 15) << 3));
    }
    __syncthreads();

    for (int c = 0; c < NCHUNK; ++c) {
        // ---- phase A: g1 for all 8 steps, 16 independent MFMAs, no syncs ----
        f32x4 g1[CH];
#pragma unroll
        for (int s = 0; s < CH; ++s) {
            const u16* xrow = &xl[(s * TROWS + l15) * IN_F];
            const bf16x8 xf0 = *(const bf16x8*)(xrow + ((hi * 8) ^ xswz));
            const bf16x8 xf1 = *(const bf16x8*)(xrow + ((32 + hi * 8) ^ xswz));
            g1[s] = __builtin_amdgcn_mfma_f32_16x16x32_bf16(xf0, w1f[0], zf, 0, 0, 0);
            g1[s] = __builtin_amdgcn_mfma_f32_16x16x32_bf16(xf1, w1f[1], g1[s], 0, 0, 0);
        }

        // ---- phase B: 8-step LIF chain in registers; z -> swizzled LDS ----
#pragma unroll
        for (int s = 0; s < CH; ++s) {
            u16* zw = &zb[s * TROWS * HHALF];
#pragma unroll
            for (int r = 0; r < 4; ++r) {
                const float vd = fmaf(dt_tau, i1[r] - v1[r], v1[r]);
                const float id = i1[r] * decay;
                const bool  sp = vd > 1.0f;
                v1[r] = sp ? 0.f : vd;
                i1[r] = id + g1[s][r];
                scnt += sp ? 1.f : 0.f;
                zw[zoff[r]] = sp ? (u16)0x3F80 : (u16)0;
            }
        }

        __syncthreads();   // barrier 1: z(group) + xl reads complete

        // ---- phase C: stage x(c+1) into xl; issue loads for x(c+2) ----
        if (c + 1 < NCHUNK) {
#pragma unroll
            for (int j = 0; j < 2; ++j)
                *(bf16x8*)&xl[wofs[j]] = pack8(ra[j], rb[j]);
            if (c + 2 < NCHUNK) {
#pragma unroll
                for (int j = 0; j < 2; ++j) {
                    const float* g = gp[j] + 2 * cstride;
                    ra[j] = *(const float4*)g;
                    rb[j] = *(const float4*)(g + 4);
                    gp[j] += cstride;
                }
            }
        }

        // ---- phase C: wave wv computes g2 for step t = 8c + wv ----
        {
            const u16* zr2 = &zb[(wv * TROWS + l15) * HHALF];
            const int rsw = l15 << 3;
            const bf16x8 z0 = *(const bf16x8*)(zr2 + ((0 * 32 + hi * 8) ^ rsw));
            const bf16x8 z1 = *(const bf16x8*)(zr2 + ((1 * 32 + hi * 8) ^ rsw));
            const bf16x8 z2 = *(const bf16x8*)(zr2 + ((2 * 32 + hi * 8) ^ rsw));
            const bf16x8 z3 = *(const bf16x8*)(zr2 + ((3 * 32 + hi * 8) ^ rsw));
            f32x4 ga = __builtin_amdgcn_mfma_f32_16x16x32_bf16(z0, w2f[0], zf, 0, 0, 0);
            f32x4 gb = __builtin_amdgcn_mfma_f32_16x16x32_bf16(z1, w2f[1], zf, 0, 0, 0);
            ga = __builtin_amdgcn_mfma_f32_16x16x32_bf16(z2, w2f[2], ga, 0, 0, 0);
            gb = __builtin_amdgcn_mfma_f32_16x16x32_bf16(z3, w2f[3], gb, 0, 0, 0);
            const f32x4 g2 = ga + gb;
            u16* dst = g2p + (size_t)half * (T_STEPS * SLAB)
                     + (size_t)(c * CH + wv) * SLAB + (row0 + 4 * hi) * OUT_F + l15;
#pragma unroll
            for (int r = 0; r < 4; ++r) dst[r * OUT_F] = f2bf(g2[r]);
        }

        __syncthreads();   // barrier 2: zb/xl free for next group
    }

    // spikes: wave reduce -> LDS -> one global atomic (integer-exact)
#pragma unroll
    for (int m = 1; m < 64; m <<= 1) scnt += __shfl_xor(scnt, m, 64);
    if (lane == 0) atomicAdd(&sacc, scnt);
    __syncthreads();
    if (tid == 0) atomicAdd(&out[BATCH * OUT_F], sacc * (1.0f / BATCH));
}

// Kernel 2: LI recurrence + max over t; one thread per (row, out) chain.
__global__ void __launch_bounds__(128)
snn_li_kernel(const u16* __restrict__ g2p, float* __restrict__ out)
{
    const int gid = blockIdx.x * 128 + threadIdx.x;    // 0..32767
    const u16* p0 = g2p + gid;
    const u16* p1 = g2p + (size_t)T_STEPS * SLAB + gid;
    const float dt_tau = (float)(0.001 * (1.0 / 0.006));
    const float decay  = (float)(1.0 - 0.001 * (1.0 / 0.006));
    float v2 = 0.f, i2 = 0.f, ymax = -1e30f;
#pragma unroll 8
    for (int t = 0; t < T_STEPS; ++t) {
        const float g = bf2f(p0[(size_t)t * SLAB]) + bf2f(p1[(size_t)t * SLAB]);
        v2 = fmaf(dt_tau, i2 - v2, v2);   // uses old i2, matches reference
        ymax = fmaxf(ymax, v2);
        i2 = i2 * decay + g;
    }
    out[gid] = ymax;
}

extern "C" void kernel_launch(void* const* d_in, const int* in_sizes, int n_in,
                              void* d_out, int out_size, void* d_ws, size_t ws_size,
                              hipStream_t stream) {
    const float* x  = (const float*)d_in[0];
    const float* w1 = (const float*)d_in[1];
    const float* w2 = (const float*)d_in[2];
    float* out = (float*)d_out;
    u16* g2p = (u16*)d_ws;   // 2 halves x 128 t x 32768 bf16 = 16 MB

    hipLaunchKernelGGL(snn_init_kernel, dim3(1), dim3(64), 0, stream, out);
    hipLaunchKernelGGL(snn_l1_kernel, dim3(256), dim3(512), 0, stream,
                       x, w1, w2, g2p, out);
    hipLaunchKernelGGL(snn_li_kernel, dim3(BATCH * OUT_F / 128), dim3(128), 0,
                       stream, g2p, out);
}